// Round 6
// baseline (485.457 us; speedup 1.0000x reference)
//
#include <hip/hip_runtime.h>
#include <hip/hip_fp16.h>
#include <math.h>

typedef _Float16 half_t;
typedef __attribute__((ext_vector_type(8))) _Float16 f16x8;  // MFMA A/B frag (4 VGPR)
typedef __attribute__((ext_vector_type(4))) float   f32x4;   // MFMA C/D frag
typedef __attribute__((ext_vector_type(4))) float   float4v;

#define IN_F   1536
#define HID    640
#define OUT_F  10
#define NBATCH 65536

#define SB() __builtin_amdgcn_sched_barrier(0)

// ---------- helpers ----------

// LDS swizzle for row-major [128][64] f16 tiles (row = 128B = 8 x 16B slots).
// byte = (row*128 + kq*16) ^ ((row&7)<<4). Reads (16 lanes, fixed kq, rows
// r..r+15): slot = kq^(r&7) -> 8 distinct, 2-way for 16 rows (free, m136).
__device__ __forceinline__ int swz64(int row, int kq) {
    int a = (row << 7) | (kq << 4);
    return a ^ ((row & 7) << 4);
}

__device__ __forceinline__ void gll16(const void* g, const void* l) {
    __builtin_amdgcn_global_load_lds(
        (const __attribute__((address_space(1))) unsigned*)g,
        (__attribute__((address_space(3))) unsigned*)l, 16, 0, 0);
}

// exact-GELU via A&S 7.1.26 erf poly (|eps|<=1.5e-7, noise vs f16 rounding)
__device__ __forceinline__ float gelu_fast(float z) {
    float x  = 0.70710678118654752f * z;
    float ax = fabsf(x);
    float t  = 1.0f / (1.0f + 0.3275911f * ax);
    float p  = t * (0.254829592f +
               t * (-0.284496736f +
               t * (1.421413741f +
               t * (-1.453152027f +
               t * 1.061405429f))));
    float e  = __expf(-ax * ax);
    float er = 1.0f - p * e;         // erf(|x|)
    er = (x < 0.0f) ? -er : er;
    return 0.5f * z * (1.0f + er);
}

// ---------- prep: mask dtype detection + masked weight build ----------

__global__ void k_detect(const unsigned* __restrict__ m, int nDwords, int* flags) {
    int f = 0, g = 0;
    for (int i = blockIdx.x * blockDim.x + threadIdx.x; i < nDwords;
         i += gridDim.x * blockDim.x) {
        unsigned d = m[i];
        f |= (d == 0x3F800000u);
        g |= (d != 0u) & (d != 1u) & (d != 0x3F800000u);
    }
    if (f) atomicOr(&flags[0], 1);
    if (g) atomicOr(&flags[1], 1);
}

__device__ __forceinline__ bool mask_at(const void* mask, int i, int isB, int isF) {
    if (isB) return ((const unsigned char*)mask)[i] != 0;
    if (isF) return ((const float*)mask)[i] != 0.0f;
    return ((const int*)mask)[i] != 0;
}

__global__ void k_mask_all(const float* __restrict__ W1, const float* __restrict__ W2,
                           const float* __restrict__ W3,
                           const void* __restrict__ m1, const void* __restrict__ m2,
                           const void* __restrict__ m3,
                           half_t* __restrict__ W1h, half_t* __restrict__ W2h,
                           float* __restrict__ W3m, const int* __restrict__ flags) {
    const int isB = flags[1], isF = flags[0];
    const int N1 = HID * IN_F, N2 = HID * HID, N3 = OUT_F * HID;
    const int NT = N1 + N2 + N3;
    for (int i = blockIdx.x * blockDim.x + threadIdx.x; i < NT;
         i += gridDim.x * blockDim.x) {
        if (i < N1) {
            W1h[i] = mask_at(m1, i, isB, isF) ? (half_t)W1[i] : (half_t)0.0f;
        } else if (i < N1 + N2) {
            int j = i - N1;
            W2h[j] = mask_at(m2, j, isB, isF) ? (half_t)W2[j] : (half_t)0.0f;
        } else {
            int j = i - N1 - N2;
            W3m[j] = mask_at(m3, j, isB, isF) ? W3[j] : 0.0f;
        }
    }
}

// ---------- fused GEMM (+ exact GELU), BK=64, counted-vmcnt depth-2 ----------
// C[m][n] = gelu( sum_k A[m][k] * W[n][k] ), C written f16 [NBATCH][HID].
// 128x128 tile, BK=64, 4 waves (2x2 of 64x64), 16x16x32 f16 MFMA, 32 MFMA/wave/step.
// LDS: 2 bufs x (A 16KB | B 16KB) = 64KB -> 2 blocks/CU.
//
// Per-iter (steady):                         outstanding VMEM at entry:
//   CVT: lgkm(0)  | nCVT: vmcnt(8)             CVT 12 = BW(ks+1)4+GL(ks+1)8
//   s_barrier (READY tile ks)                  nCVT 16 = ST(ks)8+ST(ks+1)8 -> vm(8)
//   read kk0 (8 ds_read_b128); 16 MFMA(kk0)    [compiler-interleaved, no pins]
//   read kk1 (8); lgkm(0)
//   s_barrier (CONSUMED)
//   stage(ks+2): 4 gll16 B [+ 4 gll16 A | 8 f32x4 GL->regs]
//   CVT: vmcnt(12) retire GL(ks+1); cvt+4 ds_write -> other buf A
//   16 MFMA(kk1)
template <int K, bool CVT_A>
__global__ __launch_bounds__(256, 2) void gemm_gelu(
    const void* __restrict__ Ain, const half_t* __restrict__ Bw,
    half_t* __restrict__ Cout) {
    constexpr int NK = K / 64;
    static_assert(NK >= 4 && (NK % 2 == 0), "need even NK >= 4");
    __shared__ __align__(16) char lds[65536];

    const int t    = threadIdx.x;
    const int lane = t & 63;
    const int wid  = t >> 6;
    const int wr   = wid >> 1, wc = wid & 1;

    // T1: XCD-bijective swizzle (nwg = 2560 = 8*320); n-fastest so the 5
    // n-blocks sharing an x panel are contiguous on one XCD's L2.
    const int q       = (int)gridDim.x >> 3;
    const int logical = ((int)blockIdx.x & 7) * q + ((int)blockIdx.x >> 3);
    const int mb  = logical / 5, nbk = logical - mb * 5;
    const long mBase = (long)mb * 128;
    const int  n0    = nbk * 128;

    // ds_read fragment addresses (kk=0; kk=1 is addr^0x40 since kq+4 = kq|4)
    int rdA[4], rdB[4];
    {
        const int kqg = lane >> 4;      // 0..3
        const int r   = lane & 15;
#pragma unroll
        for (int m = 0; m < 4; ++m) rdA[m] = swz64(wr * 64 + m * 16 + r, kqg);
#pragma unroll
        for (int n = 0; n < 4; ++n) rdB[n] = 16384 + swz64(wc * 64 + n * 16 + r, kqg);
    }

    // Inverse swizzle for gll16 staging of a [128][64] f16 tile:
    // dest o = t*16 + j*4096 -> row = (t>>3)+j*32, slot = t&7, kq = slot^(row&7).
    const int rowB = t >> 3;
    const int kqB  = (t & 7) ^ ((t >> 3) & 7);

    const half_t* srcB = Bw + (size_t)(n0 + rowB) * K + kqB * 8;

    const float*  srcAf = nullptr;
    const half_t* srcAh = nullptr;
    int awAddr[4];
    if constexpr (CVT_A) {
        const int rowA = t >> 1, h = t & 1;   // thread owns half a row (32 f32)
        srcAf = (const float*)Ain + (size_t)(mBase + rowA) * K + h * 32;
#pragma unroll
        for (int qq = 0; qq < 4; ++qq) awAddr[qq] = swz64(rowA, h * 4 + qq);
    } else {
        srcAh = (const half_t*)Ain + (size_t)(mBase + rowB) * K + kqB * 8;
    }

    auto BW = [&](int k, int bufb) {      // B tile: 4 gll16 (rows +0/32/64/96)
        const half_t* p = srcB + (size_t)k * 64;
#pragma unroll
        for (int j = 0; j < 4; ++j)
            gll16(p + (size_t)j * 32 * K, &lds[bufb + 16384 + t * 16 + j * 4096]);
    };
    auto AHW = [&](int k, int bufb) {     // A f16 tile via gll16 (layer 2)
        const half_t* p = srcAh + (size_t)k * 64;
#pragma unroll
        for (int j = 0; j < 4; ++j)
            gll16(p + (size_t)j * 32 * K, &lds[bufb + t * 16 + j * 4096]);
    };
    auto GL = [&](int k, float4v (&s)[8]) {   // A f32 -> regs (issue-early)
        const float* p = srcAf + (size_t)k * 64;
#pragma unroll
        for (int qq = 0; qq < 8; ++qq) s[qq] = *(const float4v*)(p + qq * 4);
    };
    auto AW = [&](const float4v (&s)[8], int bufb) {   // cvt + 4 ds_write_b128
#pragma unroll
        for (int qq = 0; qq < 4; ++qq) {
            f16x8 hh;
#pragma unroll
            for (int i = 0; i < 4; ++i) {
                hh[i]     = (half_t)s[2 * qq][i];
                hh[i + 4] = (half_t)s[2 * qq + 1][i];
            }
            *(f16x8*)(&lds[bufb + awAddr[qq]]) = hh;
        }
    };

    f32x4 acc[4][4];
#pragma unroll
    for (int m = 0; m < 4; ++m)
#pragma unroll
        for (int n = 0; n < 4; ++n) {
            f32x4 z = {0.f, 0.f, 0.f, 0.f};
            acc[m][n] = z;
        }

    auto RD = [&](int cb, int x, f16x8 (&a)[4], f16x8 (&b)[4]) {
#pragma unroll
        for (int m = 0; m < 4; ++m) a[m] = *(const f16x8*)(&lds[cb + (rdA[m] ^ x)]);
#pragma unroll
        for (int n = 0; n < 4; ++n) b[n] = *(const f16x8*)(&lds[cb + (rdB[n] ^ x)]);
    };
    auto MM16 = [&](const f16x8 (&a)[4], const f16x8 (&b)[4]) {
#pragma unroll
        for (int m = 0; m < 4; ++m)
#pragma unroll
            for (int n = 0; n < 4; ++n)
                acc[m][n] = __builtin_amdgcn_mfma_f32_16x16x32_f16(
                    a[m], b[n], acc[m][n], 0, 0, 0);
    };

    f16x8 a0[4], b0[4], a1[4], b1[4];

    if constexpr (CVT_A) {
        float4v sE[8], sO[8];
        // prologue: oldest-first BW(0)4, GL(0)8, BW(1)4, GL(1)8 = 24 outstanding
        BW(0, 0);      SB();
        GL(0, sE);     SB();
        BW(1, 32768);  SB();
        GL(1, sO);     SB();
        asm volatile("s_waitcnt vmcnt(12)" ::: "memory");  // BW(0)+GL(0) done
        AW(sE, 0);

        // citer: GLset = set[ks&1] (gets GL(ks+2)), AWset = set[(ks+1)&1]
        auto citer = [&](int ks, float4v (&glset)[8], float4v (&awset)[8]) {
            const int cb = (ks & 1) * 32768;
            asm volatile("s_waitcnt lgkmcnt(0)" ::: "memory");  // AW(ks) done
            __builtin_amdgcn_s_barrier();                        // READY ks
            RD(cb, 0, a0, b0);
            MM16(a0, b0);                   // compiler interleaves with kk1 reads
            RD(cb, 0x40, a1, b1);
            asm volatile("s_waitcnt lgkmcnt(0)" ::: "memory");   // reads drained
            __builtin_amdgcn_s_barrier();                        // CONSUMED ks
            SB(); BW(ks + 2, cb); SB(); GL(ks + 2, glset); SB();
            asm volatile("s_waitcnt vmcnt(12)" ::: "memory");    // BW+GL(ks+1) done
            AW(awset, cb ^ 32768);
            MM16(a1, b1);
        };

        // full iters ks = 0 .. NK-3 (NK even): stage always valid (ks+2 <= NK-1)
        for (int ks = 0; ks + 2 < NK; ks += 2) {
            citer(ks,     sE, sO);
            citer(ks + 1, sO, sE);
        }
        {   // ks = NK-2: no stage; retire GL(NK-1) (in sO, NK-1 odd), AW it
            const int cb = ((NK - 2) & 1) * 32768;
            asm volatile("s_waitcnt lgkmcnt(0)" ::: "memory");
            __builtin_amdgcn_s_barrier();
            RD(cb, 0, a0, b0);
            MM16(a0, b0);
            RD(cb, 0x40, a1, b1);
            asm volatile("s_waitcnt lgkmcnt(0)" ::: "memory");
            __builtin_amdgcn_s_barrier();
            asm volatile("s_waitcnt vmcnt(0)" ::: "memory");
            AW(sO, cb ^ 32768);
            MM16(a1, b1);
        }
        {   // ks = NK-1: final
            const int cb = ((NK - 1) & 1) * 32768;
            asm volatile("s_waitcnt lgkmcnt(0)" ::: "memory");
            __builtin_amdgcn_s_barrier();
            RD(cb, 0, a0, b0);
            MM16(a0, b0);
            RD(cb, 0x40, a1, b1);
            asm volatile("s_waitcnt lgkmcnt(0)" ::: "memory");
            MM16(a1, b1);
        }
    } else {
        // stage(k) = AHW(k)4 + BW(k)4 = 8 gll16; depth-2
        AHW(0, 0);     BW(0, 0);      SB();
        AHW(1, 32768); BW(1, 32768);  SB();
        for (int ks = 0; ks < NK; ++ks) {
            const int cb = (ks & 1) * 32768;
            if (ks + 1 < NK) asm volatile("s_waitcnt vmcnt(8)" ::: "memory");
            else             asm volatile("s_waitcnt vmcnt(0)" ::: "memory");
            __builtin_amdgcn_s_barrier();                        // READY ks
            RD(cb, 0, a0, b0);
            MM16(a0, b0);
            RD(cb, 0x40, a1, b1);
            asm volatile("s_waitcnt lgkmcnt(0)" ::: "memory");
            if (ks + 1 < NK) {
                __builtin_amdgcn_s_barrier();                    // CONSUMED ks
                if (ks + 2 < NK) { SB(); AHW(ks + 2, cb); BW(ks + 2, cb); SB(); }
            }
            MM16(a1, b1);
        }
    }

    // epilogue: C/D frag col=lane&15, row=(lane>>4)*4+j (m89-verified)
    const int crow0 = (lane >> 4) * 4;
    const int ccol  = lane & 15;
#pragma unroll
    for (int m = 0; m < 4; ++m)
#pragma unroll
        for (int n = 0; n < 4; ++n)
#pragma unroll
            for (int j = 0; j < 4; ++j) {
                const long row = mBase + wr * 64 + m * 16 + crow0 + j;
                const int  col = n0 + wc * 64 + n * 16 + ccol;
                Cout[row * HID + col] = (half_t)gelu_fast(acc[m][n][j]);
            }
}

// ---------- layer 3: out[b][o] = sum_k h2[b][k] * W3m[o][k], K=640, O=10 ----------
__global__ __launch_bounds__(256) void layer3_kernel(
    const half_t* __restrict__ h2, const float* __restrict__ W3m,
    float* __restrict__ out) {
    const int t = threadIdx.x, lane = t & 63, w = t >> 6;
    float w3r[OUT_F][10];
#pragma unroll
    for (int o = 0; o < OUT_F; ++o)
#pragma unroll
        for (int j = 0; j < 10; ++j)
            w3r[o][j] = W3m[o * HID + j * 64 + lane];

    for (long row = (long)blockIdx.x * 4 + w; row < NBATCH; row += (long)gridDim.x * 4) {
        float acc[OUT_F];
#pragma unroll
        for (int o = 0; o < OUT_F; ++o) acc[o] = 0.f;
        const half_t* hr = h2 + row * HID;
#pragma unroll
        for (int j = 0; j < 10; ++j) {
            const float h = (float)hr[j * 64 + lane];
#pragma unroll
            for (int o = 0; o < OUT_F; ++o) acc[o] += h * w3r[o][j];
        }
#pragma unroll
        for (int o = 0; o < OUT_F; ++o) {
            float v = acc[o];
#pragma unroll
            for (int off = 32; off >= 1; off >>= 1) v += __shfl_xor(v, off);
            if (lane == o) out[row * OUT_F + o] = v;
        }
    }
}

// ---------- launch ----------

extern "C" void kernel_launch(void* const* d_in, const int* in_sizes, int n_in,
                              void* d_out, int out_size, void* d_ws, size_t ws_size,
                              hipStream_t stream) {
    const float* x  = (const float*)d_in[0];
    const float* W1 = (const float*)d_in[1];
    const float* W2 = (const float*)d_in[2];
    const float* W3 = (const float*)d_in[3];
    const void*  m1 = d_in[4];
    const void*  m2 = d_in[5];
    const void*  m3 = d_in[6];
    float* out = (float*)d_out;

    char* ws = (char*)d_ws;
    int*    flags = (int*)ws;
    half_t* W1h = (half_t*)(ws + 256);
    half_t* W2h = (half_t*)(ws + 256 + 1966080);
    float*  W3m = (float*)(ws + 256 + 1966080 + 819200);
    half_t* h1  = (half_t*)(ws + 256 + 1966080 + 819200 + 25600);
    half_t* h2  = (half_t*)((char*)h1 + (size_t)NBATCH * HID * 2);
    // total ~162.7 MB (fits: round-1 proof)

    hipMemsetAsync(flags, 0, 8, stream);
    k_detect<<<64, 256, 0, stream>>>((const unsigned*)m1, 65536, flags);
    k_mask_all<<<1024, 256, 0, stream>>>(W1, W2, W3, m1, m2, m3, W1h, W2h, W3m, flags);

    gemm_gelu<IN_F, true><<<2560, 256, 0, stream>>>((const void*)x, W1h, h1);
    gemm_gelu<HID, false><<<2560, 256, 0, stream>>>((const void*)h1, W2h, h2);
    layer3_kernel<<<2048, 256, 0, stream>>>(h2, W3m, out);
}